// Round 9
// baseline (1035.934 us; speedup 1.0000x reference)
//
#include <hip/hip_runtime.h>
#include <hip/hip_bf16.h>

#define D 64
#define FP_SCALE 262144.0f          // 2^18 (order-free int accumulation)
#define FP_INV   (1.0f / 262144.0f)
#define NPC 128                     // nodes per chunk (LDS table = 32 KB)

__device__ __forceinline__ unsigned short f2bf(float f) {   // rtne f32->bf16
    unsigned int u = __float_as_uint(f);
    u += 0x7fffu + ((u >> 16) & 1u);
    return (unsigned short)(u >> 16);
}

// ---------- CSR build (deterministic, dst-sorted) ----------
__global__ void hist_kernel(const int* __restrict__ dst, int* __restrict__ counts, int E) {
    int e = blockIdx.x * blockDim.x + threadIdx.x;
    if (e < E) atomicAdd(&counts[dst[e]], 1);
}

// per-block(256) sums of counts
__global__ void part_kernel(const int* __restrict__ counts, int* __restrict__ partial, int N) {
    __shared__ int ws4[4];
    int t = threadIdx.x, lane = t & 63, w = t >> 6;
    int n = blockIdx.x * 256 + t;
    int c = (n < N) ? counts[n] : 0;
    #pragma unroll
    for (int off = 32; off > 0; off >>= 1) c += __shfl_down(c, off);
    if (lane == 0) ws4[w] = c;
    __syncthreads();
    if (t == 0) partial[blockIdx.x] = ws4[0] + ws4[1] + ws4[2] + ws4[3];
}

// single-block exclusive scan of partials (any nb, 512-wide passes with carry)
__global__ void scan_kernel(int* __restrict__ partial, int nb) {
    __shared__ int wsum[8];
    int t = threadIdx.x, lane = t & 63, w = t >> 6;
    int carry = 0;
    for (int base = 0; base < nb; base += 512) {
        int i = base + t;
        int v = (i < nb) ? partial[i] : 0;
        int incl = v;
        #pragma unroll
        for (int off = 1; off < 64; off <<= 1) {
            int x = __shfl_up(incl, off);
            if (lane >= off) incl += x;
        }
        if (lane == 63) wsum[w] = incl;
        __syncthreads();
        int wpre = 0;
        for (int j = 0; j < w; ++j) wpre += wsum[j];
        int tot = 0;
        for (int j = 0; j < 8; ++j) tot += wsum[j];
        if (i < nb) partial[i] = carry + wpre + incl - v;
        carry += tot;
        __syncthreads();
    }
}

// seg[n] = (global exclusive prefix, count); cursor seeded for fill.
__global__ void seg_kernel(const int* __restrict__ counts, const int* __restrict__ partial,
                           int2* __restrict__ seg, int* __restrict__ cursor, int N) {
    __shared__ int ws4[4];
    int t = threadIdx.x, lane = t & 63, w = t >> 6;
    int n = blockIdx.x * 256 + t;
    int c = (n < N) ? counts[n] : 0;
    int incl = c;
    #pragma unroll
    for (int off = 1; off < 64; off <<= 1) {
        int x = __shfl_up(incl, off);
        if (lane >= off) incl += x;
    }
    if (lane == 63) ws4[w] = incl;
    __syncthreads();
    int wpre = 0;
    for (int j = 0; j < w; ++j) wpre += ws4[j];
    int st = partial[blockIdx.x] + wpre + incl - c;
    if (n < N) {
        seg[n] = make_int2(st, c);
        cursor[n] = st;
    }
}

// perm is globally dst-sorted (scan-based starts); within-segment order is
// atomic-arrival nondeterministic, but int accumulation is order-free.
__global__ void fill_kernel(const int* __restrict__ src, const int* __restrict__ dst,
                            const float* __restrict__ ew, int* __restrict__ cursor,
                            float2* __restrict__ perm, int* __restrict__ permDst, int E) {
    int e = blockIdx.x * blockDim.x + threadIdx.x;
    if (e < E) {
        int d = dst[e];
        int p = atomicAdd(&cursor[d], 1);
        perm[p] = make_float2(__int_as_float(src[e]), ew[e] * FP_SCALE);
        permDst[p] = d;
    }
}

// f32 -> bf16 convert (for iteration 0 input)
__global__ void cvt_kernel(const float* __restrict__ in, unsigned short* __restrict__ out, int n4) {
    int i = blockIdx.x * blockDim.x + threadIdx.x;
    if (i >= n4) return;
    float4 v = reinterpret_cast<const float4*>(in)[i];
    ushort4 o;
    o.x = f2bf(v.x); o.y = f2bf(v.y); o.z = f2bf(v.z); o.w = f2bf(v.w);
    reinterpret_cast<ushort4*>(out)[i] = o;
}

// ---------- fused aggregate + linear + relu, node-partitioned ----------
// Block owns NPC=128 consecutive nodes -> its dst-sorted edge range [es,ee)
// (~1024 edges). Every node is interior by construction: no boundary atomics,
// no agg buffer, no memset; deg-0 nodes get acc=0 -> relu(b) free.
// Edge phase: 16 lane-groups own contiguous edge runs; same-dst runs
// accumulate in registers (int fixed point, order-free -> deterministic),
// flushing to the 128x64 LDS int table via atomicAdd only on dst change.
// Flush phase: wave per node, LDS broadcast b128 reads + 64 fma against
// W row in VGPRs (FP_INV folded into W; launch_bounds(256,4) = 128-VGPR
// budget keeps wreg resident), relu, coalesced store.
template<bool OUT_BF>
__launch_bounds__(256, 4)
__global__ void agg_fused_kernel(const unsigned short* __restrict__ xb,
                                 const float2* __restrict__ perm,
                                 const int* __restrict__ permDst,
                                 const int2* __restrict__ seg,
                                 const float* __restrict__ W,
                                 const float* __restrict__ bias,
                                 void* __restrict__ xout,
                                 int N, int E) {
    __shared__ int acc[NPC * D];
    int t = threadIdx.x;
    int nodeBase = blockIdx.x * NPC;
    int nodeEnd = min(nodeBase + NPC, N);
    int nNodes = nodeEnd - nodeBase;
    int es = seg[nodeBase].x;
    int ee = (nodeEnd < N) ? seg[nodeEnd].x : E;

    for (int i = t; i < nNodes * (D / 4); i += 256)
        reinterpret_cast<int4*>(acc)[i] = make_int4(0, 0, 0, 0);

    int lane = t & 63;
    float4 wreg[16];
    #pragma unroll
    for (int q = 0; q < 16; ++q) {
        float4 wv = *reinterpret_cast<const float4*>(&W[(size_t)lane * D + 4 * q]);
        wreg[q] = make_float4(wv.x * FP_INV, wv.y * FP_INV, wv.z * FP_INV, wv.w * FP_INV);
    }
    float bl = bias[lane];
    __syncthreads();

    int g = t >> 4;               // group 0..15, contiguous edge slice
    int c = (t & 15) << 2;        // feature quad
    int cnt = ee - es;
    int per = (cnt + 15) >> 4;
    int gs = es + g * per;
    int ge = min(gs + per, ee);
    if (gs < ge) {
        int cur = permDst[gs] - nodeBase;
        int a0 = 0, a1 = 0, a2 = 0, a3 = 0;
        for (int e = gs; e < ge; ++e) {
            int dn = permDst[e] - nodeBase;
            if (dn != cur) {                      // flush run (group-uniform branch)
                int s4 = cur * D + c;
                atomicAdd(&acc[s4 + 0], a0); atomicAdd(&acc[s4 + 1], a1);
                atomicAdd(&acc[s4 + 2], a2); atomicAdd(&acc[s4 + 3], a3);
                a0 = a1 = a2 = a3 = 0; cur = dn;
            }
            float2 m = perm[e];
            int s = __float_as_int(m.x);
            float w = m.y;                        // pre-scaled by 2^18
            uint2 u = *reinterpret_cast<const uint2*>(&xb[(size_t)s * D + c]);
            a0 += (int)(w * __uint_as_float(u.x << 16));
            a1 += (int)(w * __uint_as_float(u.x & 0xffff0000u));
            a2 += (int)(w * __uint_as_float(u.y << 16));
            a3 += (int)(w * __uint_as_float(u.y & 0xffff0000u));
        }
        int s4 = cur * D + c;
        atomicAdd(&acc[s4 + 0], a0); atomicAdd(&acc[s4 + 1], a1);
        atomicAdd(&acc[s4 + 2], a2); atomicAdd(&acc[s4 + 3], a3);
    }
    __syncthreads();

    int wave = t >> 6;
    for (int sIdx = wave; sIdx < nNodes; sIdx += 4) {
        float o0 = 0.f, o1 = 0.f, o2 = 0.f, o3 = 0.f;
        #pragma unroll
        for (int q = 0; q < 16; ++q) {
            int4 ai = *reinterpret_cast<const int4*>(&acc[sIdx * D + 4 * q]); // broadcast
            o0 = fmaf((float)ai.x, wreg[q].x, o0);
            o1 = fmaf((float)ai.y, wreg[q].y, o1);
            o2 = fmaf((float)ai.z, wreg[q].z, o2);
            o3 = fmaf((float)ai.w, wreg[q].w, o3);
        }
        float o = fmaxf(bl + ((o0 + o1) + (o2 + o3)), 0.0f);
        size_t off = (size_t)(nodeBase + sIdx) * D + lane;
        if (OUT_BF) ((unsigned short*)xout)[off] = f2bf(o);
        else        ((float*)xout)[off] = o;
    }
}

// ---------- fallback (int-atomic path, deterministic, f32) if ws too small ----------
__global__ void rpi_scatter_kernel(const float* __restrict__ x,
                                   const int* __restrict__ src,
                                   const int* __restrict__ dst,
                                   const float* __restrict__ ew,
                                   int* __restrict__ agg, int E) {
    int tid = blockIdx.x * blockDim.x + threadIdx.x;
    int e = tid >> 4;
    if (e >= E) return;
    int c = (tid & 15) << 2;
    int s = src[e], d = dst[e];
    float w = ew[e] * FP_SCALE;
    float4 v = *reinterpret_cast<const float4*>(&x[(size_t)s * D + c]);
    int* o = &agg[(size_t)d * D + c];
    atomicAdd(o + 0, (int)(w * v.x));
    atomicAdd(o + 1, (int)(w * v.y));
    atomicAdd(o + 2, (int)(w * v.z));
    atomicAdd(o + 3, (int)(w * v.w));
}

__global__ void rpi_linear_relu_kernel(const int* __restrict__ agg,
                                       const float* __restrict__ W,
                                       const float* __restrict__ b,
                                       float* __restrict__ out, int N) {
    __shared__ float Ws[D][D + 1];
    __shared__ float bs[D];
    int t = threadIdx.x;
    for (int i = t; i < D * D; i += 256) Ws[i >> 6][i & 63] = W[i];
    if (t < D) bs[t] = b[t];
    __syncthreads();
    int wave = t >> 6, lane = t & 63;
    int nwaves = gridDim.x * 4;
    for (int n = blockIdx.x * 4 + wave; n < N; n += nwaves) {
        const int* arow = &agg[(size_t)n * D];
        float acc = bs[lane];
        #pragma unroll
        for (int d = 0; d < D; ++d) acc = fmaf((float)arow[d] * FP_INV, Ws[lane][d], acc);
        out[(size_t)n * D + lane] = fmaxf(acc, 0.0f);
    }
}

extern "C" void kernel_launch(void* const* d_in, const int* in_sizes, int n_in,
                              void* d_out, int out_size, void* d_ws, size_t ws_size,
                              hipStream_t stream) {
    const float* x0 = (const float*)d_in[0];   // [N, 64]
    const int*   ei = (const int*)d_in[1];     // [2, E]
    const float* ew = (const float*)d_in[2];   // [E]
    const float* W  = (const float*)d_in[3];   // [64, 64]
    const float* b  = (const float*)d_in[4];   // [64]
    float* out = (float*)d_out;                // [N, 64]

    int N = in_sizes[0] / D;
    int E = in_sizes[2];
    const int* src = ei;
    const int* dst = ei + E;

    int nb = (N + 255) / 256;
    size_t xeb = (size_t)N * D * sizeof(unsigned short);   // 12.8 MB
    size_t off = 0;
    size_t o_xb1  = off; off += xeb;
    size_t o_xb2  = off; off += xeb;
    size_t o_perm = off; off += (size_t)E * sizeof(float2);
    size_t o_pdst = off; off += (size_t)E * sizeof(int);
    size_t o_seg  = off; off += (size_t)N * sizeof(int2);
    size_t o_cnt  = off; off += (size_t)N * sizeof(int);
    size_t o_part = off; off += ((size_t)nb + 16) * sizeof(int);
    size_t need = off;

    if (ws_size >= need) {
        unsigned short* xb1 = (unsigned short*)((char*)d_ws + o_xb1);
        unsigned short* xb2 = (unsigned short*)((char*)d_ws + o_xb2);
        float2* perm    = (float2*)((char*)d_ws + o_perm);
        int*    permDst = (int*)((char*)d_ws + o_pdst);
        int2*   seg     = (int2*)((char*)d_ws + o_seg);
        int*    cnt_cur = (int*)((char*)d_ws + o_cnt);   // counts, then cursor
        int*    partial = (int*)((char*)d_ws + o_part);

        int eb = (E + 255) / 256;
        int n4 = N * D / 4;
        int ab = (N + NPC - 1) / NPC;

        hipMemsetAsync(cnt_cur, 0, (size_t)N * sizeof(int), stream);
        hist_kernel<<<eb, 256, 0, stream>>>(dst, cnt_cur, E);
        part_kernel<<<nb, 256, 0, stream>>>(cnt_cur, partial, N);
        scan_kernel<<<1, 512, 0, stream>>>(partial, nb);
        seg_kernel <<<nb, 256, 0, stream>>>(cnt_cur, partial, seg, cnt_cur, N);
        fill_kernel<<<eb, 256, 0, stream>>>(src, dst, ew, cnt_cur, perm, permDst, E);
        cvt_kernel <<<(n4 + 255) / 256, 256, 0, stream>>>(x0, xb1, n4);

        agg_fused_kernel<true> <<<ab, 256, 0, stream>>>(xb1, perm, permDst, seg, W, b, xb2, N, E);
        agg_fused_kernel<true> <<<ab, 256, 0, stream>>>(xb2, perm, permDst, seg, W, b, xb1, N, E);
        agg_fused_kernel<false><<<ab, 256, 0, stream>>>(xb1, perm, permDst, seg, W, b, out, N, E);
    } else {
        int* agg = (int*)d_ws;
        const float* xcur = x0;
        int sb = (E * 16 + 255) / 256;
        for (int it = 0; it < 3; ++it) {
            hipMemsetAsync(agg, 0, (size_t)N * D * sizeof(int), stream);
            rpi_scatter_kernel<<<sb, 256, 0, stream>>>(xcur, src, dst, ew, agg, E);
            rpi_linear_relu_kernel<<<2048, 256, 0, stream>>>(agg, W, b, out, N);
            xcur = out;
        }
    }
}

// Round 10
// 852.472 us; speedup vs baseline: 1.2152x; 1.2152x over previous
//
#include <hip/hip_runtime.h>
#include <hip/hip_bf16.h>

#define D 64
#define FP_SCALE 262144.0f          // 2^18 (order-free int accumulation)
#define FP_INV   (1.0f / 262144.0f)
#define NPC 128                     // nodes per chunk (acc table = 32 KB)

__device__ __forceinline__ unsigned short f2bf(float f) {   // rtne f32->bf16
    unsigned int u = __float_as_uint(f);
    u += 0x7fffu + ((u >> 16) & 1u);
    return (unsigned short)(u >> 16);
}

// ---------- CSR build (deterministic, dst-sorted) ----------
__global__ void hist_kernel(const int* __restrict__ dst, int* __restrict__ counts, int E) {
    int e = blockIdx.x * blockDim.x + threadIdx.x;
    if (e < E) atomicAdd(&counts[dst[e]], 1);
}

// per-block(256) sums of counts
__global__ void part_kernel(const int* __restrict__ counts, int* __restrict__ partial, int N) {
    __shared__ int ws4[4];
    int t = threadIdx.x, lane = t & 63, w = t >> 6;
    int n = blockIdx.x * 256 + t;
    int c = (n < N) ? counts[n] : 0;
    #pragma unroll
    for (int off = 32; off > 0; off >>= 1) c += __shfl_down(c, off);
    if (lane == 0) ws4[w] = c;
    __syncthreads();
    if (t == 0) partial[blockIdx.x] = ws4[0] + ws4[1] + ws4[2] + ws4[3];
}

// single-block exclusive scan of partials (any nb, 512-wide passes with carry)
__global__ void scan_kernel(int* __restrict__ partial, int nb) {
    __shared__ int wsum[8];
    int t = threadIdx.x, lane = t & 63, w = t >> 6;
    int carry = 0;
    for (int base = 0; base < nb; base += 512) {
        int i = base + t;
        int v = (i < nb) ? partial[i] : 0;
        int incl = v;
        #pragma unroll
        for (int off = 1; off < 64; off <<= 1) {
            int x = __shfl_up(incl, off);
            if (lane >= off) incl += x;
        }
        if (lane == 63) wsum[w] = incl;
        __syncthreads();
        int wpre = 0;
        for (int j = 0; j < w; ++j) wpre += wsum[j];
        int tot = 0;
        for (int j = 0; j < 8; ++j) tot += wsum[j];
        if (i < nb) partial[i] = carry + wpre + incl - v;
        carry += tot;
        __syncthreads();
    }
}

// seg[n] = (global exclusive prefix, count); cursor seeded for fill.
__global__ void seg_kernel(const int* __restrict__ counts, const int* __restrict__ partial,
                           int2* __restrict__ seg, int* __restrict__ cursor, int N) {
    __shared__ int ws4[4];
    int t = threadIdx.x, lane = t & 63, w = t >> 6;
    int n = blockIdx.x * 256 + t;
    int c = (n < N) ? counts[n] : 0;
    int incl = c;
    #pragma unroll
    for (int off = 1; off < 64; off <<= 1) {
        int x = __shfl_up(incl, off);
        if (lane >= off) incl += x;
    }
    if (lane == 63) ws4[w] = incl;
    __syncthreads();
    int wpre = 0;
    for (int j = 0; j < w; ++j) wpre += ws4[j];
    int st = partial[blockIdx.x] + wpre + incl - c;
    if (n < N) {
        seg[n] = make_int2(st, c);
        cursor[n] = st;
    }
}

// perm is globally dst-sorted (scan-based starts); within-segment order is
// atomic-arrival nondeterministic, but int accumulation is order-free.
__global__ void fill_kernel(const int* __restrict__ src, const int* __restrict__ dst,
                            const float* __restrict__ ew, int* __restrict__ cursor,
                            float2* __restrict__ perm, int* __restrict__ permDst, int E) {
    int e = blockIdx.x * blockDim.x + threadIdx.x;
    if (e < E) {
        int d = dst[e];
        int p = atomicAdd(&cursor[d], 1);
        perm[p] = make_float2(__int_as_float(src[e]), ew[e] * FP_SCALE);
        permDst[p] = d;
    }
}

// f32 -> bf16 convert (for iteration 0 input)
__global__ void cvt_kernel(const float* __restrict__ in, unsigned short* __restrict__ out, int n4) {
    int i = blockIdx.x * blockDim.x + threadIdx.x;
    if (i >= n4) return;
    float4 v = reinterpret_cast<const float4*>(in)[i];
    ushort4 o;
    o.x = f2bf(v.x); o.y = f2bf(v.y); o.z = f2bf(v.z); o.w = f2bf(v.w);
    reinterpret_cast<ushort4*>(out)[i] = o;
}

// ---------- fused aggregate + linear + relu, node-partitioned ----------
// Block owns NPC=128 consecutive nodes -> dst-sorted edge range [es,ee).
// Every node interior by construction: no global atomics, no agg buffer,
// no memsets. Edge phase: 16 lane-groups own contiguous edge runs; same-dst
// runs accumulate in registers (int fixed point, order-free -> deterministic),
// flushing to the 128x64 LDS int table via atomicAdd on dst change.
// Flush phase: W lives in LDS TRANSPOSED (Wt[d][j] = W[j][d]*FP_INV): lane j
// reads Wt[d][lane] -> consecutive lanes, consecutive addresses -> 2-way bank
// aliasing (free). acc row int4 read is a same-address wave broadcast.
// NO W-in-VGPR array: rounds 7 & 9 proved the allocator spills it (VGPR=64 +
// scratch traffic blowing FETCH to 731MB).
template<bool OUT_BF>
__global__ void agg_fused_kernel(const unsigned short* __restrict__ xb,
                                 const float2* __restrict__ perm,
                                 const int* __restrict__ permDst,
                                 const int2* __restrict__ seg,
                                 const float* __restrict__ W,
                                 const float* __restrict__ bias,
                                 void* __restrict__ xout,
                                 int N, int E) {
    __shared__ int acc[NPC * D];      // 32 KB
    __shared__ float Wt[D][D];        // 16 KB, transposed + FP_INV folded
    __shared__ float bsh[D];
    int t = threadIdx.x;
    int nodeBase = blockIdx.x * NPC;
    int nodeEnd = min(nodeBase + NPC, N);
    int nNodes = nodeEnd - nodeBase;
    int es = seg[nodeBase].x;
    int ee = (nodeEnd < N) ? seg[nodeEnd].x : E;

    for (int i = t; i < NPC * (D / 4); i += 256)
        reinterpret_cast<int4*>(acc)[i] = make_int4(0, 0, 0, 0);
    for (int i = t; i < D * D; i += 256) {   // one-time transpose (write conflicts ok)
        int j = i >> 6, d = i & 63;
        Wt[d][j] = W[i] * FP_INV;
    }
    if (t < D) bsh[t] = bias[t];
    __syncthreads();

    int g = t >> 4;               // group 0..15, contiguous edge slice
    int c = (t & 15) << 2;        // feature quad
    int cnt = ee - es;
    int per = (cnt + 15) >> 4;
    int gs = es + g * per;
    int ge = min(gs + per, ee);
    if (gs < ge) {
        int cur = permDst[gs] - nodeBase;
        int a0 = 0, a1 = 0, a2 = 0, a3 = 0;
        for (int e = gs; e < ge; ++e) {
            int dn = permDst[e] - nodeBase;
            if (dn != cur) {                      // flush run (group-uniform branch)
                int s4 = cur * D + c;
                atomicAdd(&acc[s4 + 0], a0); atomicAdd(&acc[s4 + 1], a1);
                atomicAdd(&acc[s4 + 2], a2); atomicAdd(&acc[s4 + 3], a3);
                a0 = a1 = a2 = a3 = 0; cur = dn;
            }
            float2 m = perm[e];
            int s = __float_as_int(m.x);
            float w = m.y;                        // pre-scaled by 2^18
            uint2 u = *reinterpret_cast<const uint2*>(&xb[(size_t)s * D + c]);
            a0 += (int)(w * __uint_as_float(u.x << 16));
            a1 += (int)(w * __uint_as_float(u.x & 0xffff0000u));
            a2 += (int)(w * __uint_as_float(u.y << 16));
            a3 += (int)(w * __uint_as_float(u.y & 0xffff0000u));
        }
        int s4 = cur * D + c;
        atomicAdd(&acc[s4 + 0], a0); atomicAdd(&acc[s4 + 1], a1);
        atomicAdd(&acc[s4 + 2], a2); atomicAdd(&acc[s4 + 3], a3);
    }
    __syncthreads();

    int wave = t >> 6, lane = t & 63;
    for (int sIdx = wave; sIdx < nNodes; sIdx += 4) {
        float o0 = 0.f, o1 = 0.f, o2 = 0.f, o3 = 0.f;
        #pragma unroll
        for (int q = 0; q < 16; ++q) {
            int4 ai = *reinterpret_cast<const int4*>(&acc[sIdx * D + 4 * q]); // broadcast
            o0 = fmaf((float)ai.x, Wt[4 * q + 0][lane], o0);
            o1 = fmaf((float)ai.y, Wt[4 * q + 1][lane], o1);
            o2 = fmaf((float)ai.z, Wt[4 * q + 2][lane], o2);
            o3 = fmaf((float)ai.w, Wt[4 * q + 3][lane], o3);
        }
        float o = fmaxf(bsh[lane] + ((o0 + o1) + (o2 + o3)), 0.0f);
        size_t off = (size_t)(nodeBase + sIdx) * D + lane;
        if (OUT_BF) ((unsigned short*)xout)[off] = f2bf(o);
        else        ((float*)xout)[off] = o;
    }
}

// ---------- fallback (int-atomic path, deterministic, f32) if ws too small ----------
__global__ void rpi_scatter_kernel(const float* __restrict__ x,
                                   const int* __restrict__ src,
                                   const int* __restrict__ dst,
                                   const float* __restrict__ ew,
                                   int* __restrict__ agg, int E) {
    int tid = blockIdx.x * blockDim.x + threadIdx.x;
    int e = tid >> 4;
    if (e >= E) return;
    int c = (tid & 15) << 2;
    int s = src[e], d = dst[e];
    float w = ew[e] * FP_SCALE;
    float4 v = *reinterpret_cast<const float4*>(&x[(size_t)s * D + c]);
    int* o = &agg[(size_t)d * D + c];
    atomicAdd(o + 0, (int)(w * v.x));
    atomicAdd(o + 1, (int)(w * v.y));
    atomicAdd(o + 2, (int)(w * v.z));
    atomicAdd(o + 3, (int)(w * v.w));
}

__global__ void rpi_linear_relu_kernel(const int* __restrict__ agg,
                                       const float* __restrict__ W,
                                       const float* __restrict__ b,
                                       float* __restrict__ out, int N) {
    __shared__ float Ws[D][D + 1];
    __shared__ float bs[D];
    int t = threadIdx.x;
    for (int i = t; i < D * D; i += 256) Ws[i >> 6][i & 63] = W[i];
    if (t < D) bs[t] = b[t];
    __syncthreads();
    int wave = t >> 6, lane = t & 63;
    int nwaves = gridDim.x * 4;
    for (int n = blockIdx.x * 4 + wave; n < N; n += nwaves) {
        const int* arow = &agg[(size_t)n * D];
        float acc = bs[lane];
        #pragma unroll
        for (int d = 0; d < D; ++d) acc = fmaf((float)arow[d] * FP_INV, Ws[lane][d], acc);
        out[(size_t)n * D + lane] = fmaxf(acc, 0.0f);
    }
}

extern "C" void kernel_launch(void* const* d_in, const int* in_sizes, int n_in,
                              void* d_out, int out_size, void* d_ws, size_t ws_size,
                              hipStream_t stream) {
    const float* x0 = (const float*)d_in[0];   // [N, 64]
    const int*   ei = (const int*)d_in[1];     // [2, E]
    const float* ew = (const float*)d_in[2];   // [E]
    const float* W  = (const float*)d_in[3];   // [64, 64]
    const float* b  = (const float*)d_in[4];   // [64]
    float* out = (float*)d_out;                // [N, 64]

    int N = in_sizes[0] / D;
    int E = in_sizes[2];
    const int* src = ei;
    const int* dst = ei + E;

    int nb = (N + 255) / 256;
    size_t xeb = (size_t)N * D * sizeof(unsigned short);   // 12.8 MB
    size_t off = 0;
    size_t o_xb1  = off; off += xeb;
    size_t o_xb2  = off; off += xeb;
    size_t o_perm = off; off += (size_t)E * sizeof(float2);
    size_t o_pdst = off; off += (size_t)E * sizeof(int);
    size_t o_seg  = off; off += (size_t)N * sizeof(int2);
    size_t o_cnt  = off; off += (size_t)N * sizeof(int);
    size_t o_part = off; off += ((size_t)nb + 16) * sizeof(int);
    size_t need = off;

    if (ws_size >= need) {
        unsigned short* xb1 = (unsigned short*)((char*)d_ws + o_xb1);
        unsigned short* xb2 = (unsigned short*)((char*)d_ws + o_xb2);
        float2* perm    = (float2*)((char*)d_ws + o_perm);
        int*    permDst = (int*)((char*)d_ws + o_pdst);
        int2*   seg     = (int2*)((char*)d_ws + o_seg);
        int*    cnt_cur = (int*)((char*)d_ws + o_cnt);   // counts, then cursor
        int*    partial = (int*)((char*)d_ws + o_part);

        int eb = (E + 255) / 256;
        int n4 = N * D / 4;
        int ab = (N + NPC - 1) / NPC;

        hipMemsetAsync(cnt_cur, 0, (size_t)N * sizeof(int), stream);
        hist_kernel<<<eb, 256, 0, stream>>>(dst, cnt_cur, E);
        part_kernel<<<nb, 256, 0, stream>>>(cnt_cur, partial, N);
        scan_kernel<<<1, 512, 0, stream>>>(partial, nb);
        seg_kernel <<<nb, 256, 0, stream>>>(cnt_cur, partial, seg, cnt_cur, N);
        fill_kernel<<<eb, 256, 0, stream>>>(src, dst, ew, cnt_cur, perm, permDst, E);
        cvt_kernel <<<(n4 + 255) / 256, 256, 0, stream>>>(x0, xb1, n4);

        agg_fused_kernel<true> <<<ab, 256, 0, stream>>>(xb1, perm, permDst, seg, W, b, xb2, N, E);
        agg_fused_kernel<true> <<<ab, 256, 0, stream>>>(xb2, perm, permDst, seg, W, b, xb1, N, E);
        agg_fused_kernel<false><<<ab, 256, 0, stream>>>(xb1, perm, permDst, seg, W, b, out, N, E);
    } else {
        int* agg = (int*)d_ws;
        const float* xcur = x0;
        int sb = (E * 16 + 255) / 256;
        for (int it = 0; it < 3; ++it) {
            hipMemsetAsync(agg, 0, (size_t)N * D * sizeof(int), stream);
            rpi_scatter_kernel<<<sb, 256, 0, stream>>>(xcur, src, dst, ew, agg, E);
            rpi_linear_relu_kernel<<<2048, 256, 0, stream>>>(agg, W, b, out, N);
            xcur = out;
        }
    }
}

// Round 11
// 328.003 us; speedup vs baseline: 3.1583x; 2.5990x over previous
//
#include <hip/hip_runtime.h>
#include <hip/hip_bf16.h>

#define D 64
#define FP_SCALE 262144.0f          // 2^18 (order-free int accumulation)
#define FP_INV   (1.0f / 262144.0f)
#define NPC 64                      // nodes per chunk
#define ASTR 68                     // acc stride in ints (16B-aligned, padded)

__device__ __forceinline__ unsigned short f2bf(float f) {   // rtne f32->bf16
    unsigned int u = __float_as_uint(f);
    u += 0x7fffu + ((u >> 16) & 1u);
    return (unsigned short)(u >> 16);
}

// ---------- CSR build (deterministic, dst-sorted) ----------
__global__ void hist_kernel(const int* __restrict__ dst, int* __restrict__ counts, int E) {
    int e = blockIdx.x * blockDim.x + threadIdx.x;
    if (e < E) atomicAdd(&counts[dst[e]], 1);
}

__global__ void part_kernel(const int* __restrict__ counts, int* __restrict__ partial, int N) {
    __shared__ int ws4[4];
    int t = threadIdx.x, lane = t & 63, w = t >> 6;
    int n = blockIdx.x * 256 + t;
    int c = (n < N) ? counts[n] : 0;
    #pragma unroll
    for (int off = 32; off > 0; off >>= 1) c += __shfl_down(c, off);
    if (lane == 0) ws4[w] = c;
    __syncthreads();
    if (t == 0) partial[blockIdx.x] = ws4[0] + ws4[1] + ws4[2] + ws4[3];
}

__global__ void scan_kernel(int* __restrict__ partial, int nb) {
    __shared__ int wsum[8];
    int t = threadIdx.x, lane = t & 63, w = t >> 6;
    int carry = 0;
    for (int base = 0; base < nb; base += 512) {
        int i = base + t;
        int v = (i < nb) ? partial[i] : 0;
        int incl = v;
        #pragma unroll
        for (int off = 1; off < 64; off <<= 1) {
            int x = __shfl_up(incl, off);
            if (lane >= off) incl += x;
        }
        if (lane == 63) wsum[w] = incl;
        __syncthreads();
        int wpre = 0;
        for (int j = 0; j < w; ++j) wpre += wsum[j];
        int tot = 0;
        for (int j = 0; j < 8; ++j) tot += wsum[j];
        if (i < nb) partial[i] = carry + wpre + incl - v;
        carry += tot;
        __syncthreads();
    }
}

// cursor[n] = global exclusive prefix; blockStart[b] = prefix at node b*NPC.
__global__ void seg_kernel(const int* __restrict__ counts, const int* __restrict__ partial,
                           int* __restrict__ cursor, int* __restrict__ blockStart, int N) {
    __shared__ int ws4[4];
    int t = threadIdx.x, lane = t & 63, w = t >> 6;
    int n = blockIdx.x * 256 + t;
    int c = (n < N) ? counts[n] : 0;
    int incl = c;
    #pragma unroll
    for (int off = 1; off < 64; off <<= 1) {
        int x = __shfl_up(incl, off);
        if (lane >= off) incl += x;
    }
    if (lane == 63) ws4[w] = incl;
    __syncthreads();
    int wpre = 0;
    for (int j = 0; j < w; ++j) wpre += ws4[j];
    int st = partial[blockIdx.x] + wpre + incl - c;
    if (n < N) {
        cursor[n] = st;
        if ((n & (NPC - 1)) == 0) blockStart[n / NPC] = st;
    }
}

// Pack (w*2^18, src, slot=dst&63) into one uint64 per edge. Placement within a
// segment is atomic-order nondeterministic, but the aggregate's integer
// accumulation is order-free -> output is a pure function of the inputs.
__global__ void fill_kernel(const int* __restrict__ src, const int* __restrict__ dst,
                            const float* __restrict__ ew, int* __restrict__ cursor,
                            unsigned long long* __restrict__ perm64, int E) {
    int e = blockIdx.x * blockDim.x + threadIdx.x;
    if (e < E) {
        int d = dst[e];
        int p = atomicAdd(&cursor[d], 1);
        unsigned lo = ((unsigned)src[e] << 6) | (unsigned)(d & (NPC - 1));
        perm64[p] = ((unsigned long long)__float_as_uint(ew[e] * FP_SCALE) << 32) | lo;
    }
}

// f32 -> bf16 convert (for iteration 0 input)
__global__ void cvt_kernel(const float* __restrict__ in, unsigned short* __restrict__ out, int n4) {
    int i = blockIdx.x * blockDim.x + threadIdx.x;
    if (i >= n4) return;
    float4 v = reinterpret_cast<const float4*>(in)[i];
    ushort4 o;
    o.x = f2bf(v.x); o.y = f2bf(v.y); o.z = f2bf(v.z); o.w = f2bf(v.w);
    reinterpret_cast<ushort4*>(out)[i] = o;
}

// ---------- fused aggregate + linear + relu, node-partitioned ----------
// Block owns NPC=64 consecutive nodes -> dst-sorted edge range [es,ee) (~512).
// Edge phase (round-8-proven shape): 16-lane groups stride the edge range,
// per-edge direct LDS atomicAdd, NO loop-carried state -> compiler pipelines
// loads across iterations (round 9/10's run-accumulation serialized on a
// data-dependent branch: 264us vs round 8's 63us).
// Flush phase: register-blocked. Each wave owns 16 nodes with o[16] static-
// indexed accumulators; W read once per feature from LDS (64 b32/wave, not
// 1024); acc rows via same-address int4 broadcast. No W-in-VGPR array
// (rounds 7/9: allocator spills it -> scratch blows FETCH to 177-731MB).
template<bool OUT_BF>
__global__ void agg_fused_kernel(const unsigned short* __restrict__ xb,
                                 const unsigned long long* __restrict__ perm64,
                                 const int* __restrict__ blockStart,
                                 const float* __restrict__ W,
                                 const float* __restrict__ bias,
                                 void* __restrict__ xout,
                                 int N, int E) {
    __shared__ int acc[NPC * ASTR];   // 17 KB
    __shared__ float Wt[D][D];        // 16 KB, transposed + FP_INV folded
    __shared__ float bsh[D];
    int t = threadIdx.x;
    int bid = blockIdx.x;
    int nodeBase = bid * NPC;
    int nodeEnd = min(nodeBase + NPC, N);
    int es = blockStart[bid];
    int ee = (bid + 1 < (int)gridDim.x) ? blockStart[bid + 1] : E;

    for (int i = t; i < NPC * ASTR / 4; i += 256)
        reinterpret_cast<int4*>(acc)[i] = make_int4(0, 0, 0, 0);
    for (int i = t; i < D * D; i += 256) {   // one-time transpose
        int j = i >> 6, d = i & 63;
        Wt[d][j] = W[i] * FP_INV;
    }
    if (t < D) bsh[t] = bias[t];
    __syncthreads();

    int g = t >> 4;               // group 0..15
    int c = (t & 15) << 2;        // feature quad base
    for (int e = es + g; e < ee; e += 16) {   // no loop-carried state
        unsigned long long pk = perm64[e];    // 8B, broadcast within group
        unsigned lo = (unsigned)pk;
        float w = __uint_as_float((unsigned)(pk >> 32));
        int slot = (int)(lo & (NPC - 1));
        int s = (int)(lo >> 6);
        uint2 u = *reinterpret_cast<const uint2*>(&xb[(size_t)s * D + c]);
        int base = slot * ASTR + c;
        atomicAdd(&acc[base + 0], (int)(w * __uint_as_float(u.x << 16)));
        atomicAdd(&acc[base + 1], (int)(w * __uint_as_float(u.x & 0xffff0000u)));
        atomicAdd(&acc[base + 2], (int)(w * __uint_as_float(u.y << 16)));
        atomicAdd(&acc[base + 3], (int)(w * __uint_as_float(u.y & 0xffff0000u)));
    }
    __syncthreads();

    int wave = t >> 6, lane = t & 63;
    int sBase = wave * 16;                    // this wave's 16 nodes
    float o[16];
    #pragma unroll
    for (int i = 0; i < 16; ++i) o[i] = 0.f;
    for (int f = 0; f < D; f += 4) {
        float w0 = Wt[f + 0][lane];           // consecutive lanes: conflict-free
        float w1 = Wt[f + 1][lane];
        float w2 = Wt[f + 2][lane];
        float w3 = Wt[f + 3][lane];
        #pragma unroll
        for (int i = 0; i < 16; ++i) {
            int4 ai = *reinterpret_cast<const int4*>(&acc[(sBase + i) * ASTR + f]); // broadcast
            o[i] = fmaf((float)ai.x, w0,
                   fmaf((float)ai.y, w1,
                   fmaf((float)ai.z, w2,
                   fmaf((float)ai.w, w3, o[i]))));
        }
    }
    #pragma unroll
    for (int i = 0; i < 16; ++i) {
        int node = nodeBase + sBase + i;
        if (node < nodeEnd) {
            float v = fmaxf(bsh[lane] + o[i], 0.0f);
            size_t off = (size_t)node * D + lane;
            if (OUT_BF) ((unsigned short*)xout)[off] = f2bf(v);
            else        ((float*)xout)[off] = v;
        }
    }
}

// ---------- fallback (int-atomic path, deterministic, f32) if ws too small ----------
__global__ void rpi_scatter_kernel(const float* __restrict__ x,
                                   const int* __restrict__ src,
                                   const int* __restrict__ dst,
                                   const float* __restrict__ ew,
                                   int* __restrict__ agg, int E) {
    int tid = blockIdx.x * blockDim.x + threadIdx.x;
    int e = tid >> 4;
    if (e >= E) return;
    int c = (tid & 15) << 2;
    int s = src[e], d = dst[e];
    float w = ew[e] * FP_SCALE;
    float4 v = *reinterpret_cast<const float4*>(&x[(size_t)s * D + c]);
    int* o = &agg[(size_t)d * D + c];
    atomicAdd(o + 0, (int)(w * v.x));
    atomicAdd(o + 1, (int)(w * v.y));
    atomicAdd(o + 2, (int)(w * v.z));
    atomicAdd(o + 3, (int)(w * v.w));
}

__global__ void rpi_linear_relu_kernel(const int* __restrict__ agg,
                                       const float* __restrict__ W,
                                       const float* __restrict__ b,
                                       float* __restrict__ out, int N) {
    __shared__ float Ws[D][D + 1];
    __shared__ float bs[D];
    int t = threadIdx.x;
    for (int i = t; i < D * D; i += 256) Ws[i >> 6][i & 63] = W[i];
    if (t < D) bs[t] = b[t];
    __syncthreads();
    int wave = t >> 6, lane = t & 63;
    int nwaves = gridDim.x * 4;
    for (int n = blockIdx.x * 4 + wave; n < N; n += nwaves) {
        const int* arow = &agg[(size_t)n * D];
        float acc = bs[lane];
        #pragma unroll
        for (int d = 0; d < D; ++d) acc = fmaf((float)arow[d] * FP_INV, Ws[lane][d], acc);
        out[(size_t)n * D + lane] = fmaxf(acc, 0.0f);
    }
}

extern "C" void kernel_launch(void* const* d_in, const int* in_sizes, int n_in,
                              void* d_out, int out_size, void* d_ws, size_t ws_size,
                              hipStream_t stream) {
    const float* x0 = (const float*)d_in[0];   // [N, 64]
    const int*   ei = (const int*)d_in[1];     // [2, E]
    const float* ew = (const float*)d_in[2];   // [E]
    const float* W  = (const float*)d_in[3];   // [64, 64]
    const float* b  = (const float*)d_in[4];   // [64]
    float* out = (float*)d_out;                // [N, 64]

    int N = in_sizes[0] / D;
    int E = in_sizes[2];
    const int* src = ei;
    const int* dst = ei + E;

    int nb   = (N + 255) / 256;
    int nblk = (N + NPC - 1) / NPC;
    size_t xeb = (size_t)N * D * sizeof(unsigned short);   // 12.8 MB
    size_t off = 0;
    size_t o_xb1  = off; off += xeb;
    size_t o_xb2  = off; off += xeb;
    size_t o_p64  = off; off += (size_t)E * sizeof(unsigned long long);
    size_t o_cnt  = off; off += (size_t)N * sizeof(int);
    size_t o_part = off; off += ((size_t)nb + 16) * sizeof(int);
    size_t o_bs   = off; off += ((size_t)nblk + 2) * sizeof(int);
    size_t need = off;

    if (ws_size >= need) {
        unsigned short* xb1 = (unsigned short*)((char*)d_ws + o_xb1);
        unsigned short* xb2 = (unsigned short*)((char*)d_ws + o_xb2);
        unsigned long long* perm64 = (unsigned long long*)((char*)d_ws + o_p64);
        int* cnt_cur    = (int*)((char*)d_ws + o_cnt);   // counts, then cursor
        int* partial    = (int*)((char*)d_ws + o_part);
        int* blockStart = (int*)((char*)d_ws + o_bs);

        int eb = (E + 255) / 256;
        int n4 = N * D / 4;

        hipMemsetAsync(cnt_cur, 0, (size_t)N * sizeof(int), stream);
        hist_kernel<<<eb, 256, 0, stream>>>(dst, cnt_cur, E);
        part_kernel<<<nb, 256, 0, stream>>>(cnt_cur, partial, N);
        scan_kernel<<<1, 512, 0, stream>>>(partial, nb);
        seg_kernel <<<nb, 256, 0, stream>>>(cnt_cur, partial, cnt_cur, blockStart, N);
        fill_kernel<<<eb, 256, 0, stream>>>(src, dst, ew, cnt_cur, perm64, E);
        cvt_kernel <<<(n4 + 255) / 256, 256, 0, stream>>>(x0, xb1, n4);

        agg_fused_kernel<true> <<<nblk, 256, 0, stream>>>(xb1, perm64, blockStart, W, b, xb2, N, E);
        agg_fused_kernel<true> <<<nblk, 256, 0, stream>>>(xb2, perm64, blockStart, W, b, xb1, N, E);
        agg_fused_kernel<false><<<nblk, 256, 0, stream>>>(xb1, perm64, blockStart, W, b, out, N, E);
    } else {
        int* agg = (int*)d_ws;
        const float* xcur = x0;
        int sb = (E * 16 + 255) / 256;
        for (int it = 0; it < 3; ++it) {
            hipMemsetAsync(agg, 0, (size_t)N * D * sizeof(int), stream);
            rpi_scatter_kernel<<<sb, 256, 0, stream>>>(xcur, src, dst, ew, agg, E);
            rpi_linear_relu_kernel<<<2048, 256, 0, stream>>>(agg, W, b, out, N);
            xcur = out;
        }
    }
}

// Round 12
// 313.697 us; speedup vs baseline: 3.3023x; 1.0456x over previous
//
#include <hip/hip_runtime.h>
#include <hip/hip_bf16.h>

#define D 64
#define FP_SCALE 262144.0f          // 2^18 (order-free int accumulation)
#define FP_INV   (1.0f / 262144.0f)
#define NPC 64                      // nodes per chunk
#define ASTR 65                     // odd acc stride (ints) — breaks mod-4 bank class

__device__ __forceinline__ unsigned short f2bf(float f) {   // rtne f32->bf16
    unsigned int u = __float_as_uint(f);
    u += 0x7fffu + ((u >> 16) & 1u);
    return (unsigned short)(u >> 16);
}

// ---------- CSR build (deterministic, dst-sorted) ----------
__global__ void hist_kernel(const int* __restrict__ dst, int* __restrict__ counts, int E) {
    int e = blockIdx.x * blockDim.x + threadIdx.x;
    if (e < E) atomicAdd(&counts[dst[e]], 1);
}

__global__ void part_kernel(const int* __restrict__ counts, int* __restrict__ partial, int N) {
    __shared__ int ws4[4];
    int t = threadIdx.x, lane = t & 63, w = t >> 6;
    int n = blockIdx.x * 256 + t;
    int c = (n < N) ? counts[n] : 0;
    #pragma unroll
    for (int off = 32; off > 0; off >>= 1) c += __shfl_down(c, off);
    if (lane == 0) ws4[w] = c;
    __syncthreads();
    if (t == 0) partial[blockIdx.x] = ws4[0] + ws4[1] + ws4[2] + ws4[3];
}

__global__ void scan_kernel(int* __restrict__ partial, int nb) {
    __shared__ int wsum[8];
    int t = threadIdx.x, lane = t & 63, w = t >> 6;
    int carry = 0;
    for (int base = 0; base < nb; base += 512) {
        int i = base + t;
        int v = (i < nb) ? partial[i] : 0;
        int incl = v;
        #pragma unroll
        for (int off = 1; off < 64; off <<= 1) {
            int x = __shfl_up(incl, off);
            if (lane >= off) incl += x;
        }
        if (lane == 63) wsum[w] = incl;
        __syncthreads();
        int wpre = 0;
        for (int j = 0; j < w; ++j) wpre += wsum[j];
        int tot = 0;
        for (int j = 0; j < 8; ++j) tot += wsum[j];
        if (i < nb) partial[i] = carry + wpre + incl - v;
        carry += tot;
        __syncthreads();
    }
}

// cursor[n] = global exclusive prefix; blockStart[b] = prefix at node b*NPC.
__global__ void seg_kernel(const int* __restrict__ counts, const int* __restrict__ partial,
                           int* __restrict__ cursor, int* __restrict__ blockStart, int N) {
    __shared__ int ws4[4];
    int t = threadIdx.x, lane = t & 63, w = t >> 6;
    int n = blockIdx.x * 256 + t;
    int c = (n < N) ? counts[n] : 0;
    int incl = c;
    #pragma unroll
    for (int off = 1; off < 64; off <<= 1) {
        int x = __shfl_up(incl, off);
        if (lane >= off) incl += x;
    }
    if (lane == 63) ws4[w] = incl;
    __syncthreads();
    int wpre = 0;
    for (int j = 0; j < w; ++j) wpre += ws4[j];
    int st = partial[blockIdx.x] + wpre + incl - c;
    if (n < N) {
        cursor[n] = st;
        if ((n & (NPC - 1)) == 0) blockStart[n / NPC] = st;
    }
}

// Pack (w*2^18, src, slot=dst&63) into one uint64 per edge. Placement within a
// segment is atomic-order nondeterministic, but the aggregate's integer
// accumulation is order-free -> output is a pure function of the inputs.
__global__ void fill_kernel(const int* __restrict__ src, const int* __restrict__ dst,
                            const float* __restrict__ ew, int* __restrict__ cursor,
                            unsigned long long* __restrict__ perm64, int E) {
    int e = blockIdx.x * blockDim.x + threadIdx.x;
    if (e < E) {
        int d = dst[e];
        int p = atomicAdd(&cursor[d], 1);
        unsigned lo = ((unsigned)src[e] << 6) | (unsigned)(d & (NPC - 1));
        perm64[p] = ((unsigned long long)__float_as_uint(ew[e] * FP_SCALE) << 32) | lo;
    }
}

// f32 -> bf16 convert (for iteration 0 input)
__global__ void cvt_kernel(const float* __restrict__ in, unsigned short* __restrict__ out, int n4) {
    int i = blockIdx.x * blockDim.x + threadIdx.x;
    if (i >= n4) return;
    float4 v = reinterpret_cast<const float4*>(in)[i];
    ushort4 o;
    o.x = f2bf(v.x); o.y = f2bf(v.y); o.z = f2bf(v.z); o.w = f2bf(v.w);
    reinterpret_cast<ushort4*>(out)[i] = o;
}

// ---------- fused aggregate + linear + relu, node-partitioned ----------
// Block owns NPC=64 consecutive nodes -> dst-sorted edge range [es,ee) (~512).
// LDS layout (swizzled, ASTR=65 odd): feature f of slot s lives at word
//   s*65 + (f&3)*16 + (f>>2)
// so atomic instruction j (lane i handles features 4i..4i+3) addresses
// s*65 + j*16 + i -> 16 CONSECUTIVE banks per instruction (round 11's
// slot*68+4i+j put all atomics in one 8-bank mod-4 class -> 8-way, 11M
// conflict cycles). Edge mapping gives each group 4 consecutive edges per
// iter while a wave's 4 groups sit 16 edges (~2 slots) apart -> no
// same-address contention; the r=0..3 batch is a natural unroll x4 (4 perm
// loads then 4 independent gathers in flight).
template<bool OUT_BF>
__global__ void agg_fused_kernel(const unsigned short* __restrict__ xb,
                                 const unsigned long long* __restrict__ perm64,
                                 const int* __restrict__ blockStart,
                                 const float* __restrict__ W,
                                 const float* __restrict__ bias,
                                 void* __restrict__ xout,
                                 int N, int E) {
    __shared__ int acc[NPC * ASTR];   // 16.6 KB
    __shared__ float Wt[D][D];        // 16 KB, transposed + FP_INV folded
    __shared__ float bsh[D];
    int t = threadIdx.x;
    int bid = blockIdx.x;
    int nodeBase = bid * NPC;
    int nodeEnd = min(nodeBase + NPC, N);
    int es = blockStart[bid];
    int ee = (bid + 1 < (int)gridDim.x) ? blockStart[bid + 1] : E;

    for (int i = t; i < NPC * ASTR / 4; i += 256)
        reinterpret_cast<int4*>(acc)[i] = make_int4(0, 0, 0, 0);
    for (int i = t; i < D * D; i += 256) {   // one-time transpose
        int j = i >> 6, d = i & 63;
        Wt[d][j] = W[i] * FP_INV;
    }
    if (t < D) bsh[t] = bias[t];
    __syncthreads();

    int g = t >> 4;               // group 0..15 (16 lanes each)
    int i16 = t & 15;             // lane within group; handles features 4*i16..+3
    int gl = g & 3;               // position within wave
    int w4 = g >> 2;              // wave index

    // macro: accumulate one edge's packed record into swizzled LDS
#define EDGE_ATOMIC(pk)                                                         \
    {                                                                           \
        unsigned lo_ = (unsigned)(pk);                                          \
        float w_ = __uint_as_float((unsigned)((pk) >> 32));                     \
        int slot_ = (int)(lo_ & (NPC - 1));                                     \
        int s_ = (int)(lo_ >> 6);                                               \
        uint2 u_ = *reinterpret_cast<const uint2*>(&xb[(size_t)s_ * D + (i16 << 2)]); \
        int base_ = slot_ * ASTR + i16;                                         \
        atomicAdd(&acc[base_ +  0], (int)(w_ * __uint_as_float(u_.x << 16)));   \
        atomicAdd(&acc[base_ + 16], (int)(w_ * __uint_as_float(u_.x & 0xffff0000u))); \
        atomicAdd(&acc[base_ + 32], (int)(w_ * __uint_as_float(u_.y << 16)));   \
        atomicAdd(&acc[base_ + 48], (int)(w_ * __uint_as_float(u_.y & 0xffff0000u))); \
    }

    // main loop: 64 edges per k across the block; this group's 4 edges are
    // consecutive; wave's groups are 16 apart.
    int myOff = es + gl * 16 + w4 * 4;
    int cnt = ee - es;
    int kmax = cnt >> 6;                       // full 64-edge super-blocks
    for (int k = 0; k < kmax; ++k) {
        int e0 = myOff + (k << 6);
        unsigned long long pk0 = perm64[e0 + 0];
        unsigned long long pk1 = perm64[e0 + 1];
        unsigned long long pk2 = perm64[e0 + 2];
        unsigned long long pk3 = perm64[e0 + 3];
        EDGE_ATOMIC(pk0); EDGE_ATOMIC(pk1); EDGE_ATOMIC(pk2); EDGE_ATOMIC(pk3);
    }
    // tail: remaining edges, per-edge stride-16 over groups
    for (int e = es + (kmax << 6) + g; e < ee; e += 16) {
        unsigned long long pk = perm64[e];
        EDGE_ATOMIC(pk);
    }
#undef EDGE_ATOMIC
    __syncthreads();

    // flush: wave owns 16 nodes; un-swizzle with 4 scalar broadcast reads
    int wave = t >> 6, lane = t & 63;
    int sBase = wave * 16;
    float o[16];
    #pragma unroll
    for (int i = 0; i < 16; ++i) o[i] = 0.f;
    for (int q = 0; q < 16; ++q) {            // feature quad q -> feats 4q..4q+3
        float w0 = Wt[4 * q + 0][lane];       // consecutive lanes: conflict-free
        float w1 = Wt[4 * q + 1][lane];
        float w2 = Wt[4 * q + 2][lane];
        float w3 = Wt[4 * q + 3][lane];
        #pragma unroll
        for (int i = 0; i < 16; ++i) {
            int base = (sBase + i) * ASTR + q;
            float a0 = (float)acc[base +  0]; // broadcast reads
            float a1 = (float)acc[base + 16];
            float a2 = (float)acc[base + 32];
            float a3 = (float)acc[base + 48];
            o[i] = fmaf(a0, w0, fmaf(a1, w1, fmaf(a2, w2, fmaf(a3, w3, o[i]))));
        }
    }
    #pragma unroll
    for (int i = 0; i < 16; ++i) {
        int node = nodeBase + sBase + i;
        if (node < nodeEnd) {
            float v = fmaxf(bsh[lane] + o[i], 0.0f);
            size_t off = (size_t)node * D + lane;
            if (OUT_BF) ((unsigned short*)xout)[off] = f2bf(v);
            else        ((float*)xout)[off] = v;
        }
    }
}

// ---------- fallback (int-atomic path, deterministic, f32) if ws too small ----------
__global__ void rpi_scatter_kernel(const float* __restrict__ x,
                                   const int* __restrict__ src,
                                   const int* __restrict__ dst,
                                   const float* __restrict__ ew,
                                   int* __restrict__ agg, int E) {
    int tid = blockIdx.x * blockDim.x + threadIdx.x;
    int e = tid >> 4;
    if (e >= E) return;
    int c = (tid & 15) << 2;
    int s = src[e], d = dst[e];
    float w = ew[e] * FP_SCALE;
    float4 v = *reinterpret_cast<const float4*>(&x[(size_t)s * D + c]);
    int* o = &agg[(size_t)d * D + c];
    atomicAdd(o + 0, (int)(w * v.x));
    atomicAdd(o + 1, (int)(w * v.y));
    atomicAdd(o + 2, (int)(w * v.z));
    atomicAdd(o + 3, (int)(w * v.w));
}

__global__ void rpi_linear_relu_kernel(const int* __restrict__ agg,
                                       const float* __restrict__ W,
                                       const float* __restrict__ b,
                                       float* __restrict__ out, int N) {
    __shared__ float Ws[D][D + 1];
    __shared__ float bs[D];
    int t = threadIdx.x;
    for (int i = t; i < D * D; i += 256) Ws[i >> 6][i & 63] = W[i];
    if (t < D) bs[t] = b[t];
    __syncthreads();
    int wave = t >> 6, lane = t & 63;
    int nwaves = gridDim.x * 4;
    for (int n = blockIdx.x * 4 + wave; n < N; n += nwaves) {
        const int* arow = &agg[(size_t)n * D];
        float acc = bs[lane];
        #pragma unroll
        for (int d = 0; d < D; ++d) acc = fmaf((float)arow[d] * FP_INV, Ws[lane][d], acc);
        out[(size_t)n * D + lane] = fmaxf(acc, 0.0f);
    }
}

extern "C" void kernel_launch(void* const* d_in, const int* in_sizes, int n_in,
                              void* d_out, int out_size, void* d_ws, size_t ws_size,
                              hipStream_t stream) {
    const float* x0 = (const float*)d_in[0];   // [N, 64]
    const int*   ei = (const int*)d_in[1];     // [2, E]
    const float* ew = (const float*)d_in[2];   // [E]
    const float* W  = (const float*)d_in[3];   // [64, 64]
    const float* b  = (const float*)d_in[4];   // [64]
    float* out = (float*)d_out;                // [N, 64]

    int N = in_sizes[0] / D;
    int E = in_sizes[2];
    const int* src = ei;
    const int* dst = ei + E;

    int nb   = (N + 255) / 256;
    int nblk = (N + NPC - 1) / NPC;
    size_t xeb = (size_t)N * D * sizeof(unsigned short);   // 12.8 MB
    size_t off = 0;
    size_t o_xb1  = off; off += xeb;
    size_t o_xb2  = off; off += xeb;
    size_t o_p64  = off; off += (size_t)E * sizeof(unsigned long long);
    size_t o_cnt  = off; off += (size_t)N * sizeof(int);
    size_t o_part = off; off += ((size_t)nb + 16) * sizeof(int);
    size_t o_bs   = off; off += ((size_t)nblk + 2) * sizeof(int);
    size_t need = off;

    if (ws_size >= need) {
        unsigned short* xb1 = (unsigned short*)((char*)d_ws + o_xb1);
        unsigned short* xb2 = (unsigned short*)((char*)d_ws + o_xb2);
        unsigned long long* perm64 = (unsigned long long*)((char*)d_ws + o_p64);
        int* cnt_cur    = (int*)((char*)d_ws + o_cnt);   // counts, then cursor
        int* partial    = (int*)((char*)d_ws + o_part);
        int* blockStart = (int*)((char*)d_ws + o_bs);

        int eb = (E + 255) / 256;
        int n4 = N * D / 4;

        hipMemsetAsync(cnt_cur, 0, (size_t)N * sizeof(int), stream);
        hist_kernel<<<eb, 256, 0, stream>>>(dst, cnt_cur, E);
        part_kernel<<<nb, 256, 0, stream>>>(cnt_cur, partial, N);
        scan_kernel<<<1, 512, 0, stream>>>(partial, nb);
        seg_kernel <<<nb, 256, 0, stream>>>(cnt_cur, partial, cnt_cur, blockStart, N);
        fill_kernel<<<eb, 256, 0, stream>>>(src, dst, ew, cnt_cur, perm64, E);
        cvt_kernel <<<(n4 + 255) / 256, 256, 0, stream>>>(x0, xb1, n4);

        agg_fused_kernel<true> <<<nblk, 256, 0, stream>>>(xb1, perm64, blockStart, W, b, xb2, N, E);
        agg_fused_kernel<true> <<<nblk, 256, 0, stream>>>(xb2, perm64, blockStart, W, b, xb1, N, E);
        agg_fused_kernel<false><<<nblk, 256, 0, stream>>>(xb1, perm64, blockStart, W, b, out, N, E);
    } else {
        int* agg = (int*)d_ws;
        const float* xcur = x0;
        int sb = (E * 16 + 255) / 256;
        for (int it = 0; it < 3; ++it) {
            hipMemsetAsync(agg, 0, (size_t)N * D * sizeof(int), stream);
            rpi_scatter_kernel<<<sb, 256, 0, stream>>>(xcur, src, dst, ew, agg, E);
            rpi_linear_relu_kernel<<<2048, 256, 0, stream>>>(agg, W, b, out, N);
            xcur = out;
        }
    }
}